// Round 2
// baseline (757.359 us; speedup 1.0000x reference)
//
#include <hip/hip_runtime.h>
#include <hip/hip_bf16.h>
#include <stdint.h>

#define NB 16
#define CDIM 96
#define HW 112
#define NPOS (HW*HW)      // 12544
#define NHEAD 3
#define DH 32
#define WN 16             // windows per side
#define NWIN (WN*WN)      // 256 windows per image

// ---------- bf16 helpers ----------
__device__ __forceinline__ float bfbits_lo(uint32_t w){ union{uint32_t u; float f;} a; a.u = w<<16; return a.f; }
__device__ __forceinline__ float bfbits_hi(uint32_t w){ union{uint32_t u; float f;} a; a.u = w & 0xFFFF0000u; return a.f; }
__device__ __forceinline__ uint32_t packbf(float x, float y){
  union{float f; uint32_t u;} a, b; a.f = x; b.f = y;
  uint32_t ua = a.u + 0x7FFFu + ((a.u>>16)&1u);
  uint32_t ub = b.u + 0x7FFFu + ((b.u>>16)&1u);
  return (ua>>16) | (ub & 0xFFFF0000u);
}

// ---------- K0: transpose weights ----------
__global__ void k_transpose_w(const float* __restrict__ wqkv, const float* __restrict__ wproj,
                              float* __restrict__ wqkvT, float* __restrict__ wprojT){
  int n = blockIdx.x*256 + threadIdx.x;
  if (n < 288*96){ int o = n/96, c = n%96; wqkvT[c*288+o] = wqkv[n]; }
  if (n < 96*96){ int o = n/96, c = n%96; wprojT[c*96+o] = wproj[n]; }
}

// ---------- K1: 7x7 mean pool + leaky relu ----------
__global__ void k_pool_act(const float* __restrict__ x, float* __restrict__ act){
  int n = blockIdx.x*256 + threadIdx.x;        // 393216 = (b*96+c)*256 + wh*16+ww
  int ww = n & 15; int wh = (n>>4)&15; int bc = n>>8;
  const float* src = x + (size_t)bc*NPOS + (size_t)(wh*7)*HW + ww*7;
  float s = 0.f;
  #pragma unroll
  for (int r=0;r<7;r++){
    const float* row = src + r*HW;
    s += row[0]+row[1]+row[2]+row[3]+row[4]+row[5]+row[6];
  }
  s *= (1.f/49.f);
  act[n] = s > 0.f ? s : 0.01f*s;
}

// ---------- K2: offsets / scales per window ----------
__global__ void k_offscl(const float* __restrict__ act,
                         const float* __restrict__ woff, const float* __restrict__ boff,
                         const float* __restrict__ wscl, const float* __restrict__ bscl,
                         float4* __restrict__ offscl){
  int n = blockIdx.x*256 + threadIdx.x;        // 4096 = b*256 + wh*16+ww
  int b = n >> 8; int wpos = n & 255;
  float accO[6], accS[6];
  #pragma unroll
  for (int o=0;o<6;o++){ accO[o]=boff[o]; accS[o]=bscl[o]; }
  const float* a = act + (size_t)b*CDIM*NWIN + wpos;
  for (int c=0;c<CDIM;c++){
    float av = a[(size_t)c*NWIN];
    #pragma unroll
    for (int o=0;o<6;o++){ accO[o] += av*woff[o*CDIM+c]; accS[o] += av*wscl[o*CDIM+c]; }
  }
  #pragma unroll
  for (int h=0;h<NHEAD;h++){
    float4 r;
    r.x = accO[2*h]   * (1.f/16.f);   // off_x / (h//ws)
    r.y = accO[2*h+1] * (1.f/16.f);   // off_y / (w//ws)
    r.z = accS[2*h];                  // scl_x
    r.w = accS[2*h+1];                // scl_y
    offscl[(size_t)(b*NHEAD+h)*NWIN + wpos] = r;
  }
}

// ---------- K3: qkv projection GEMM (f32 compute, bf16 out, channel-last layout) ----------
__launch_bounds__(256)
__global__ void k_qkv(const float* __restrict__ x, const float* __restrict__ wT,
                      const float* __restrict__ bias,
                      uint32_t* __restrict__ q, uint32_t* __restrict__ k, uint32_t* __restrict__ v){
  __shared__ float ldsX[CDIM*128];
  int b = blockIdx.x / 98; int p0 = (blockIdx.x % 98)*128;
  {
    float4* l4 = (float4*)ldsX;
    #pragma unroll
    for (int i=0;i<12;i++){
      int f = threadIdx.x + i*256;           // float4 index, 3072 total
      int c = f >> 5; int po = (f & 31)*4;
      l4[f] = *(const float4*)(x + (size_t)(b*CDIM+c)*NPOS + p0 + po);
    }
  }
  __syncthreads();
  int lane = threadIdx.x & 63; int og = threadIdx.x >> 6;   // 4 ogroups x 24 outs
  #pragma unroll
  for (int s=0;s<3;s++){
    float accA[24], accB[24];
    #pragma unroll
    for (int oo=0;oo<24;oo++){ float bv = bias[s*96+og*24+oo]; accA[oo]=bv; accB[oo]=bv; }
    for (int c=0;c<CDIM;c++){
      float xa = ldsX[c*128+lane], xb = ldsX[c*128+lane+64];
      const float4* w4 = (const float4*)(wT + c*288 + s*96 + og*24);
      #pragma unroll
      for (int j=0;j<6;j++){
        float4 w = w4[j];
        accA[j*4+0] += w.x*xa; accA[j*4+1] += w.y*xa; accA[j*4+2] += w.z*xa; accA[j*4+3] += w.w*xa;
        accB[j*4+0] += w.x*xb; accB[j*4+1] += w.y*xb; accB[j*4+2] += w.z*xb; accB[j*4+3] += w.w*xb;
      }
    }
    uint32_t* dst = (s==0) ? q : ((s==1) ? k : v);
    #pragma unroll
    for (int oo=0;oo<24;oo+=2){
      int o = og*24+oo; int h = o>>5; int d = o&31;
      size_t base = ((size_t)(b*NHEAD+h)*NPOS + p0)*DH + d;   // bf16 element index
      dst[(base + (size_t)lane*DH)>>1]      = packbf(accA[oo], accA[oo+1]);
      dst[(base + (size_t)(lane+64)*DH)>>1] = packbf(accB[oo], accB[oo+1]);
    }
  }
}

// ---------- K4: fused bilinear sample + window attention ----------
__device__ __forceinline__ void load_row_fma(const uint32_t* __restrict__ src, float w, float* acc){
  const uint4* p4 = (const uint4*)src;
  #pragma unroll
  for (int r=0;r<4;r++){
    uint4 u = p4[r];
    acc[r*8+0] += w*bfbits_lo(u.x); acc[r*8+1] += w*bfbits_hi(u.x);
    acc[r*8+2] += w*bfbits_lo(u.y); acc[r*8+3] += w*bfbits_hi(u.y);
    acc[r*8+4] += w*bfbits_lo(u.z); acc[r*8+5] += w*bfbits_hi(u.z);
    acc[r*8+6] += w*bfbits_lo(u.w); acc[r*8+7] += w*bfbits_hi(u.w);
  }
}

__launch_bounds__(64)
__global__ void k_attn(const uint32_t* __restrict__ qb, const uint32_t* __restrict__ kb,
                       const uint32_t* __restrict__ vb, const float4* __restrict__ offscl,
                       const float* __restrict__ rpb, float* __restrict__ aout){
  __shared__ float kw[49*32];
  __shared__ float vw[49*32];
  int head = blockIdx.x % 3; int win = blockIdx.x / 3;
  int b = win >> 8; int wh = (win>>4)&15; int ww = win & 15;
  int bh = b*NHEAD + head;
  float4 os = offscl[(size_t)bh*NWIN + (wh*16+ww)];
  int t = threadIdx.x;
  float qreg[32];
  if (t < 49){
    int qi = t/7, qj = t%7;
    { // q row (no resampling for q)
      size_t base = ((size_t)bh*NPOS + (size_t)(wh*7+qi)*HW + ww*7+qj)*DH;
      const uint4* qp = (const uint4*)(qb + (base>>1));
      #pragma unroll
      for (int r=0;r<4;r++){
        uint4 u = qp[r];
        qreg[r*8+0]=bfbits_lo(u.x); qreg[r*8+1]=bfbits_hi(u.x);
        qreg[r*8+2]=bfbits_lo(u.y); qreg[r*8+3]=bfbits_hi(u.y);
        qreg[r*8+4]=bfbits_lo(u.z); qreg[r*8+5]=bfbits_hi(u.z);
        qreg[r*8+6]=bfbits_lo(u.w); qreg[r*8+7]=bfbits_hi(u.w);
      }
    }
    // sample coordinates: px = X + (j-3)*sclx + 55.5*offx  (exact algebra of the ref)
    float px = (float)(ww*7+qj) + (float)(qj-3)*os.z + 55.5f*os.x;
    float py = (float)(wh*7+qi) + (float)(qi-3)*os.w + 55.5f*os.y;
    float x0f = floorf(px), y0f = floorf(py);
    float fx = px-x0f, fy = py-y0f;
    int x0 = (int)x0f, y0 = (int)y0f;
    float krow[32], vrow[32];
    #pragma unroll
    for (int d=0;d<32;d++){ krow[d]=0.f; vrow[d]=0.f; }
    float wts0 = (1.f-fx)*(1.f-fy), wts1 = fx*(1.f-fy), wts2 = (1.f-fx)*fy, wts3 = fx*fy;
    #pragma unroll
    for (int nb=0; nb<4; nb++){
      int xi = (nb&1) ? x0+1 : x0;
      int yi = (nb&2) ? y0+1 : y0;
      float wgt = (nb==0)?wts0:((nb==1)?wts1:((nb==2)?wts2:wts3));
      if (xi>=0 && xi<HW && yi>=0 && yi<HW){
        size_t base = ((size_t)bh*NPOS + (size_t)yi*HW + xi)*DH;
        load_row_fma(kb + (base>>1), wgt, krow);
        load_row_fma(vb + (base>>1), wgt, vrow);
      }
    }
    // XOR-swizzled LDS write (avoid bank conflicts of 128B-stride rows)
    #pragma unroll
    for (int j=0;j<8;j++){
      int pj = j ^ (t&7);
      *(float4*)(kw + t*32 + pj*4) = make_float4(krow[j*4],krow[j*4+1],krow[j*4+2],krow[j*4+3]);
      *(float4*)(vw + t*32 + pj*4) = make_float4(vrow[j*4],vrow[j*4+1],vrow[j*4+2],vrow[j*4+3]);
    }
  }
  __syncthreads();
  if (t < 49){
    int qi = t/7, qj = t%7;
    float p[49];
    float m = -1e30f;
    #pragma unroll
    for (int kk=0;kk<49;kk++){
      float dot = 0.f;
      #pragma unroll
      for (int j=0;j<8;j++){
        const float4 kv = *(const float4*)(kw + kk*32 + ((j ^ (kk&7))*4));
        dot += kv.x*qreg[j*4+0] + kv.y*qreg[j*4+1] + kv.z*qreg[j*4+2] + kv.w*qreg[j*4+3];
      }
      int dy = qi - kk/7 + 6, dx = qj - kk%7 + 6;
      float bias = rpb[(dy*13+dx)*3 + head];
      float sval = dot*0.17677669529663687f + bias;
      p[kk] = sval;
      m = fmaxf(m, sval);
    }
    float l = 0.f;
    #pragma unroll
    for (int kk=0;kk<49;kk++){ float e = __expf(p[kk]-m); p[kk]=e; l+=e; }
    float rl = 1.f/l;
    float o_acc[32];
    #pragma unroll
    for (int d=0;d<32;d++) o_acc[d]=0.f;
    #pragma unroll
    for (int kk=0;kk<49;kk++){
      float a = p[kk]*rl;
      #pragma unroll
      for (int j=0;j<8;j++){
        const float4 vv = *(const float4*)(vw + kk*32 + ((j ^ (kk&7))*4));
        o_acc[j*4+0]+=a*vv.x; o_acc[j*4+1]+=a*vv.y; o_acc[j*4+2]+=a*vv.z; o_acc[j*4+3]+=a*vv.w;
      }
    }
    // write channel-major f32 directly into d_out: aout[b][head*32+d][y*112+x]
    size_t sp = (size_t)(wh*7+qi)*HW + ww*7+qj;
    float* dst = aout + ((size_t)b*CDIM + head*DH)*NPOS + sp;
    #pragma unroll
    for (int d=0;d<32;d++) dst[(size_t)d*NPOS] = o_acc[d];
  }
}

// ---------- K5: output projection GEMM, IN PLACE on d_out (f32 in, f32 out) ----------
// Safe: each block stages its entire (96ch x 128pos) input slice into LDS,
// __syncthreads, then writes only that same (b, pos) slice. Blocks touch
// disjoint slices. No __restrict__ on the aliased pointers.
__launch_bounds__(256)
__global__ void k_proj(const float* attnout, const float* __restrict__ wT,
                       const float* __restrict__ bias, float* out){
  __shared__ float ldsX[CDIM*128];
  int b = blockIdx.x / 98; int p0 = (blockIdx.x % 98)*128;
  {
    float4* l4 = (float4*)ldsX;
    #pragma unroll
    for (int i=0;i<12;i++){
      int f = threadIdx.x + i*256;           // float4 index, 3072 total
      int c = f >> 5; int po = (f & 31)*4;
      l4[f] = *(const float4*)(attnout + (size_t)(b*CDIM+c)*NPOS + p0 + po);
    }
  }
  __syncthreads();
  int lane = threadIdx.x & 63; int og = threadIdx.x >> 6;
  float accA[24], accB[24];
  #pragma unroll
  for (int oo=0;oo<24;oo++){ float bv = bias[og*24+oo]; accA[oo]=bv; accB[oo]=bv; }
  for (int c=0;c<CDIM;c++){
    float xa = ldsX[c*128+lane], xb = ldsX[c*128+lane+64];
    const float4* w4 = (const float4*)(wT + c*96 + og*24);
    #pragma unroll
    for (int j=0;j<6;j++){
      float4 w = w4[j];
      accA[j*4+0] += w.x*xa; accA[j*4+1] += w.y*xa; accA[j*4+2] += w.z*xa; accA[j*4+3] += w.w*xa;
      accB[j*4+0] += w.x*xb; accB[j*4+1] += w.y*xb; accB[j*4+2] += w.z*xb; accB[j*4+3] += w.w*xb;
    }
  }
  #pragma unroll
  for (int oo=0;oo<24;oo++){
    int o = og*24+oo;
    float* dst = out + (size_t)(b*CDIM+o)*NPOS + p0;
    dst[lane] = accA[oo]; dst[lane+64] = accB[oo];
  }
}

extern "C" void kernel_launch(void* const* d_in, const int* in_sizes, int n_in,
                              void* d_out, int out_size, void* d_ws, size_t ws_size,
                              hipStream_t stream) {
  const float* x      = (const float*)d_in[0];
  const float* w_qkv  = (const float*)d_in[1];
  const float* b_qkv  = (const float*)d_in[2];
  const float* w_off  = (const float*)d_in[3];
  const float* b_off  = (const float*)d_in[4];
  const float* w_scl  = (const float*)d_in[5];
  const float* b_scl  = (const float*)d_in[6];
  const float* rpb    = (const float*)d_in[7];
  const float* w_proj = (const float*)d_in[8];
  const float* b_proj = (const float*)d_in[9];

  // ---- workspace map (act is 1,572,864 BYTES = 393,216 floats!) ----
  char* ws = (char*)d_ws;
  float*   act    = (float*)(ws + 0);                 // 1,572,864 B
  float4*  offscl = (float4*)(ws + 1572864);          //   196,608 B
  float*   wqkvT  = (float*)(ws + 1769472);           //   110,592 B
  float*   wprojT = (float*)(ws + 1880064);           //    36,864 B
  const size_t QKV_BYTES = (size_t)NB*NHEAD*NPOS*DH*2; // 38,535,168 B each (bf16)
  uint32_t* qbuf = (uint32_t*)(ws + 2097152);
  uint32_t* kbuf = (uint32_t*)(ws + 2097152 + QKV_BYTES);
  uint32_t* vbuf = (uint32_t*)(ws + 2097152 + 2*QKV_BYTES);
  // total: 2,097,152 + 3*38,535,168 = 117,702,656 B (~112.3 MB)

  hipLaunchKernelGGL(k_transpose_w, dim3(108), dim3(256), 0, stream, w_qkv, w_proj, wqkvT, wprojT);
  hipLaunchKernelGGL(k_pool_act,    dim3(1536), dim3(256), 0, stream, x, act);
  hipLaunchKernelGGL(k_offscl,      dim3(16),   dim3(256), 0, stream, act, w_off, b_off, w_scl, b_scl, offscl);
  hipLaunchKernelGGL(k_qkv,         dim3(16*98), dim3(256), 0, stream, x, wqkvT, b_qkv, qbuf, kbuf, vbuf);
  hipLaunchKernelGGL(k_attn,        dim3(4096*3), dim3(64), 0, stream, qbuf, kbuf, vbuf, offscl, rpb, (float*)d_out);
  hipLaunchKernelGGL(k_proj,        dim3(16*98), dim3(256), 0, stream, (const float*)d_out, wprojT, b_proj, (float*)d_out);
}

// Round 3
// 257.125 us; speedup vs baseline: 2.9455x; 2.9455x over previous
//
#include <hip/hip_runtime.h>
#include <hip/hip_bf16.h>
#include <stdint.h>

#define NB 16
#define CDIM 96
#define HW 112
#define NPOS (HW*HW)      // 12544
#define NHEAD 3
#define DH 32
#define WN 16
#define NWIN (WN*WN)

typedef __attribute__((ext_vector_type(8))) short bf16x8;
typedef __attribute__((ext_vector_type(4))) float f32x4;

// ---------- bf16 helpers ----------
__device__ __forceinline__ float bfbits_lo(uint32_t w){ union{uint32_t u; float f;} a; a.u = w<<16; return a.f; }
__device__ __forceinline__ float bfbits_hi(uint32_t w){ union{uint32_t u; float f;} a; a.u = w & 0xFFFF0000u; return a.f; }
__device__ __forceinline__ uint32_t packbf(float x, float y){
  union{float f; uint32_t u;} a, b; a.f = x; b.f = y;
  uint32_t ua = a.u + 0x7FFFu + ((a.u>>16)&1u);
  uint32_t ub = b.u + 0x7FFFu + ((b.u>>16)&1u);
  return (ua>>16) | (ub & 0xFFFF0000u);
}
__device__ __forceinline__ unsigned short f2bf(float x){
  union{float f; uint32_t u;} a; a.f = x;
  return (unsigned short)((a.u + 0x7FFFu + ((a.u>>16)&1u))>>16);
}

// ---------- K1: 7x7 mean pool + leaky relu ----------
__global__ void k_pool_act(const float* __restrict__ x, float* __restrict__ act){
  int n = blockIdx.x*256 + threadIdx.x;
  int ww = n & 15; int wh = (n>>4)&15; int bc = n>>8;
  const float* src = x + (size_t)bc*NPOS + (size_t)(wh*7)*HW + ww*7;
  float s = 0.f;
  #pragma unroll
  for (int r=0;r<7;r++){
    const float* row = src + r*HW;
    s += row[0]+row[1]+row[2]+row[3]+row[4]+row[5]+row[6];
  }
  s *= (1.f/49.f);
  act[n] = s > 0.f ? s : 0.01f*s;
}

// ---------- K2: offsets / scales per window ----------
__global__ void k_offscl(const float* __restrict__ act,
                         const float* __restrict__ woff, const float* __restrict__ boff,
                         const float* __restrict__ wscl, const float* __restrict__ bscl,
                         float4* __restrict__ offscl){
  int n = blockIdx.x*256 + threadIdx.x;
  int b = n >> 8; int wpos = n & 255;
  float accO[6], accS[6];
  #pragma unroll
  for (int o=0;o<6;o++){ accO[o]=boff[o]; accS[o]=bscl[o]; }
  const float* a = act + (size_t)b*CDIM*NWIN + wpos;
  for (int c=0;c<CDIM;c++){
    float av = a[(size_t)c*NWIN];
    #pragma unroll
    for (int o=0;o<6;o++){ accO[o] += av*woff[o*CDIM+c]; accS[o] += av*wscl[o*CDIM+c]; }
  }
  #pragma unroll
  for (int h=0;h<NHEAD;h++){
    float4 r;
    r.x = accO[2*h]   * (1.f/16.f);
    r.y = accO[2*h+1] * (1.f/16.f);
    r.z = accS[2*h];
    r.w = accS[2*h+1];
    offscl[(size_t)(b*NHEAD+h)*NWIN + wpos] = r;
  }
}

// ---------- K3: qkv projection via bf16 MFMA ----------
// Block: one batch b, 64-position tile. A = x^T tile [64 pos][96 k] bf16 (padded 104),
// B = w_qkv natural [out][k] bf16 (padded 104). C[pos][out] per 16x16x32 MFMA.
__launch_bounds__(256)
__global__ void k_qkv_mfma(const float* __restrict__ x, const float* __restrict__ wqkv,
                           const float* __restrict__ bqkv,
                           unsigned short* __restrict__ q, unsigned short* __restrict__ kk,
                           unsigned short* __restrict__ v){
  __shared__ float xf[96*72];        // f32 stage [c][72]
  __shared__ uint4 xbf4[64*13];      // bf16 [64 pos][104 ch] (208 B rows)
  __shared__ uint4 wbf4[96*13];      // bf16 [96 out][104 ch]
  const int t = threadIdx.x;
  const int b = blockIdx.x / 196;
  const int p0 = (blockIdx.x % 196) * 64;

  // Phase A: coalesced f32 stage
  #pragma unroll
  for (int i=0;i<6;i++){
    int f = t + i*256; int c = f>>4; int p4 = (f&15)*4;
    *(float4*)(xf + c*72 + p4) = *(const float4*)(x + (size_t)(b*CDIM+c)*NPOS + p0 + p4);
  }
  __syncthreads();
  // Phase B: in-LDS transpose -> bf16 [pos][ch]
  #pragma unroll
  for (int i=0;i<3;i++){
    int u = t + i*256; int pos = u & 63; int oct = u >> 6;   // oct 0..11
    uint32_t pk0 = packbf(xf[(oct*8+0)*72+pos], xf[(oct*8+1)*72+pos]);
    uint32_t pk1 = packbf(xf[(oct*8+2)*72+pos], xf[(oct*8+3)*72+pos]);
    uint32_t pk2 = packbf(xf[(oct*8+4)*72+pos], xf[(oct*8+5)*72+pos]);
    uint32_t pk3 = packbf(xf[(oct*8+6)*72+pos], xf[(oct*8+7)*72+pos]);
    xbf4[pos*13 + oct] = make_uint4(pk0,pk1,pk2,pk3);
  }

  const int lane = t & 63, wv = t >> 6;
  const int g = lane >> 4, r16 = lane & 15;

  for (int s=0;s<3;s++){
    if (s) __syncthreads();          // prior MFMA done before wbf overwrite
    // stage W_s: natural [out][ch] layout, f32 -> bf16
    #pragma unroll
    for (int i=0;i<9;i++){
      int f = t + i*256; int o = f/24; int c4m = f%24;       // c = c4m*4
      float4 wvv = *(const float4*)(wqkv + (size_t)(s*96+o)*CDIM + c4m*4);
      ((uint2*)wbf4)[o*26 + c4m] = make_uint2(packbf(wvv.x,wvv.y), packbf(wvv.z,wvv.w));
    }
    __syncthreads();

    f32x4 acc[6];
    #pragma unroll
    for (int nf=0;nf<6;nf++) acc[nf] = (f32x4){0.f,0.f,0.f,0.f};
    #pragma unroll
    for (int ks=0;ks<3;ks++){
      bf16x8 a = *(const bf16x8*)&xbf4[(wv*16 + r16)*13 + ks*4 + g];
      #pragma unroll
      for (int nf=0;nf<6;nf++){
        bf16x8 bb = *(const bf16x8*)&wbf4[(nf*16 + r16)*13 + ks*4 + g];
        acc[nf] = __builtin_amdgcn_mfma_f32_16x16x32_bf16(a, bb, acc[nf], 0,0,0);
      }
    }
    unsigned short* dst = (s==0)?q:((s==1)?kk:v);
    #pragma unroll
    for (int nf=0;nf<6;nf++){
      int o = nf*16 + r16; int h = o>>5; int d = o&31;
      float bv = bqkv[s*96+o];
      size_t base = ((size_t)(b*NHEAD+h)*NPOS + p0 + wv*16 + g*4)*DH + d;
      #pragma unroll
      for (int rr=0;rr<4;rr++)
        dst[base + (size_t)rr*DH] = f2bf(acc[nf][rr] + bv);
    }
  }
}

// ---------- K4: fused bilinear sample + window attention ----------
__device__ __forceinline__ void load_row_fma(const uint32_t* __restrict__ src, float w, float* acc){
  const uint4* p4 = (const uint4*)src;
  #pragma unroll
  for (int r=0;r<4;r++){
    uint4 u = p4[r];
    acc[r*8+0] += w*bfbits_lo(u.x); acc[r*8+1] += w*bfbits_hi(u.x);
    acc[r*8+2] += w*bfbits_lo(u.y); acc[r*8+3] += w*bfbits_hi(u.y);
    acc[r*8+4] += w*bfbits_lo(u.z); acc[r*8+5] += w*bfbits_hi(u.z);
    acc[r*8+6] += w*bfbits_lo(u.w); acc[r*8+7] += w*bfbits_hi(u.w);
  }
}

__launch_bounds__(64)
__global__ void k_attn(const uint32_t* __restrict__ qb, const uint32_t* __restrict__ kb,
                       const uint32_t* __restrict__ vb, const float4* __restrict__ offscl,
                       const float* __restrict__ rpb, float* __restrict__ aout){
  __shared__ float kw[49*32];
  __shared__ float vw[49*32];
  int head = blockIdx.x % 3; int win = blockIdx.x / 3;
  int b = win >> 8; int wh = (win>>4)&15; int ww = win & 15;
  int bh = b*NHEAD + head;
  float4 os = offscl[(size_t)bh*NWIN + (wh*16+ww)];
  int t = threadIdx.x;
  float qreg[32];
  if (t < 49){
    int qi = t/7, qj = t%7;
    {
      size_t base = ((size_t)bh*NPOS + (size_t)(wh*7+qi)*HW + ww*7+qj)*DH;
      const uint4* qp = (const uint4*)(qb + (base>>1));
      #pragma unroll
      for (int r=0;r<4;r++){
        uint4 u = qp[r];
        qreg[r*8+0]=bfbits_lo(u.x); qreg[r*8+1]=bfbits_hi(u.x);
        qreg[r*8+2]=bfbits_lo(u.y); qreg[r*8+3]=bfbits_hi(u.y);
        qreg[r*8+4]=bfbits_lo(u.z); qreg[r*8+5]=bfbits_hi(u.z);
        qreg[r*8+6]=bfbits_lo(u.w); qreg[r*8+7]=bfbits_hi(u.w);
      }
    }
    float px = (float)(ww*7+qj) + (float)(qj-3)*os.z + 55.5f*os.x;
    float py = (float)(wh*7+qi) + (float)(qi-3)*os.w + 55.5f*os.y;
    float x0f = floorf(px), y0f = floorf(py);
    float fx = px-x0f, fy = py-y0f;
    int x0 = (int)x0f, y0 = (int)y0f;
    float krow[32], vrow[32];
    #pragma unroll
    for (int d=0;d<32;d++){ krow[d]=0.f; vrow[d]=0.f; }
    float wts0 = (1.f-fx)*(1.f-fy), wts1 = fx*(1.f-fy), wts2 = (1.f-fx)*fy, wts3 = fx*fy;
    #pragma unroll
    for (int nb=0; nb<4; nb++){
      int xi = (nb&1) ? x0+1 : x0;
      int yi = (nb&2) ? y0+1 : y0;
      float wgt = (nb==0)?wts0:((nb==1)?wts1:((nb==2)?wts2:wts3));
      if (xi>=0 && xi<HW && yi>=0 && yi<HW){
        size_t base = ((size_t)bh*NPOS + (size_t)yi*HW + xi)*DH;
        load_row_fma(kb + (base>>1), wgt, krow);
        load_row_fma(vb + (base>>1), wgt, vrow);
      }
    }
    #pragma unroll
    for (int j=0;j<8;j++){
      int pj = j ^ (t&7);
      *(float4*)(kw + t*32 + pj*4) = make_float4(krow[j*4],krow[j*4+1],krow[j*4+2],krow[j*4+3]);
      *(float4*)(vw + t*32 + pj*4) = make_float4(vrow[j*4],vrow[j*4+1],vrow[j*4+2],vrow[j*4+3]);
    }
  }
  __syncthreads();
  if (t < 49){
    int qi = t/7, qj = t%7;
    float p[49];
    float m = -1e30f;
    #pragma unroll
    for (int kx=0;kx<49;kx++){
      float dot = 0.f;
      #pragma unroll
      for (int j=0;j<8;j++){
        const float4 kv = *(const float4*)(kw + kx*32 + ((j ^ (kx&7))*4));
        dot += kv.x*qreg[j*4+0] + kv.y*qreg[j*4+1] + kv.z*qreg[j*4+2] + kv.w*qreg[j*4+3];
      }
      int dy = qi - kx/7 + 6, dx = qj - kx%7 + 6;
      float bias = rpb[(dy*13+dx)*3 + head];
      float sval = dot*0.17677669529663687f + bias;
      p[kx] = sval;
      m = fmaxf(m, sval);
    }
    float l = 0.f;
    #pragma unroll
    for (int kx=0;kx<49;kx++){ float e = __expf(p[kx]-m); p[kx]=e; l+=e; }
    float rl = 1.f/l;
    float o_acc[32];
    #pragma unroll
    for (int d=0;d<32;d++) o_acc[d]=0.f;
    #pragma unroll
    for (int kx=0;kx<49;kx++){
      float a = p[kx]*rl;
      #pragma unroll
      for (int j=0;j<8;j++){
        const float4 vv = *(const float4*)(vw + kx*32 + ((j ^ (kx&7))*4));
        o_acc[j*4+0]+=a*vv.x; o_acc[j*4+1]+=a*vv.y; o_acc[j*4+2]+=a*vv.z; o_acc[j*4+3]+=a*vv.w;
      }
    }
    size_t sp = (size_t)(wh*7+qi)*HW + ww*7+qj;
    float* dst = aout + ((size_t)b*CDIM + head*DH)*NPOS + sp;
    #pragma unroll
    for (int d=0;d<32;d++) dst[(size_t)d*NPOS] = o_acc[d];
  }
}

// ---------- K5: output projection via bf16 MFMA, IN PLACE on d_out ----------
// Safe in-place: block stages its whole [96ch x 64pos] input slice to LDS
// (Phase A), syncs, then writes only that same slice.
__launch_bounds__(256)
__global__ void k_proj_mfma(const float* yin, const float* __restrict__ wproj,
                            const float* __restrict__ bproj, float* yout){
  __shared__ float xf[96*72];
  __shared__ uint4 xbf4[64*13];
  __shared__ uint4 wbf4[96*13];
  const int t = threadIdx.x;
  const int b = blockIdx.x / 196;
  const int p0 = (blockIdx.x % 196) * 64;

  #pragma unroll
  for (int i=0;i<6;i++){
    int f = t + i*256; int c = f>>4; int p4 = (f&15)*4;
    *(float4*)(xf + c*72 + p4) = *(const float4*)(yin + (size_t)(b*CDIM+c)*NPOS + p0 + p4);
  }
  __syncthreads();
  #pragma unroll
  for (int i=0;i<3;i++){
    int u = t + i*256; int pos = u & 63; int oct = u >> 6;
    uint32_t pk0 = packbf(xf[(oct*8+0)*72+pos], xf[(oct*8+1)*72+pos]);
    uint32_t pk1 = packbf(xf[(oct*8+2)*72+pos], xf[(oct*8+3)*72+pos]);
    uint32_t pk2 = packbf(xf[(oct*8+4)*72+pos], xf[(oct*8+5)*72+pos]);
    uint32_t pk3 = packbf(xf[(oct*8+6)*72+pos], xf[(oct*8+7)*72+pos]);
    xbf4[pos*13 + oct] = make_uint4(pk0,pk1,pk2,pk3);
  }
  #pragma unroll
  for (int i=0;i<9;i++){
    int f = t + i*256; int o = f/24; int c4m = f%24;
    float4 wvv = *(const float4*)(wproj + (size_t)o*CDIM + c4m*4);
    ((uint2*)wbf4)[o*26 + c4m] = make_uint2(packbf(wvv.x,wvv.y), packbf(wvv.z,wvv.w));
  }
  __syncthreads();

  const int lane = t & 63, wv = t >> 6;
  const int g = lane >> 4, r16 = lane & 15;
  f32x4 acc[6];
  #pragma unroll
  for (int nf=0;nf<6;nf++) acc[nf] = (f32x4){0.f,0.f,0.f,0.f};
  #pragma unroll
  for (int ks=0;ks<3;ks++){
    bf16x8 a = *(const bf16x8*)&xbf4[(wv*16 + r16)*13 + ks*4 + g];
    #pragma unroll
    for (int nf=0;nf<6;nf++){
      bf16x8 bb = *(const bf16x8*)&wbf4[(nf*16 + r16)*13 + ks*4 + g];
      acc[nf] = __builtin_amdgcn_mfma_f32_16x16x32_bf16(a, bb, acc[nf], 0,0,0);
    }
  }
  #pragma unroll
  for (int nf=0;nf<6;nf++){
    int o = nf*16 + r16;
    float bv = bproj[o];
    float* dst = yout + (size_t)(b*CDIM+o)*NPOS + p0 + wv*16 + g*4;
    #pragma unroll
    for (int rr=0;rr<4;rr++) dst[rr] = acc[nf][rr] + bv;
  }
}

extern "C" void kernel_launch(void* const* d_in, const int* in_sizes, int n_in,
                              void* d_out, int out_size, void* d_ws, size_t ws_size,
                              hipStream_t stream) {
  const float* x      = (const float*)d_in[0];
  const float* w_qkv  = (const float*)d_in[1];
  const float* b_qkv  = (const float*)d_in[2];
  const float* w_off  = (const float*)d_in[3];
  const float* b_off  = (const float*)d_in[4];
  const float* w_scl  = (const float*)d_in[5];
  const float* b_scl  = (const float*)d_in[6];
  const float* rpb    = (const float*)d_in[7];
  const float* w_proj = (const float*)d_in[8];
  const float* b_proj = (const float*)d_in[9];

  char* ws = (char*)d_ws;
  float*   act    = (float*)(ws + 0);                  // 1,572,864 B
  float4*  offscl = (float4*)(ws + 1572864);           //   196,608 B
  const size_t QKV_BYTES = (size_t)NB*NHEAD*NPOS*DH*2; // 38,535,168 B each
  unsigned short* qbuf = (unsigned short*)(ws + 2097152);
  unsigned short* kbuf = (unsigned short*)(ws + 2097152 + QKV_BYTES);
  unsigned short* vbuf = (unsigned short*)(ws + 2097152 + 2*QKV_BYTES);

  hipLaunchKernelGGL(k_pool_act,  dim3(1536), dim3(256), 0, stream, x, act);
  hipLaunchKernelGGL(k_offscl,    dim3(16),   dim3(256), 0, stream, act, w_off, b_off, w_scl, b_scl, offscl);
  hipLaunchKernelGGL(k_qkv_mfma,  dim3(16*196), dim3(256), 0, stream, x, w_qkv, b_qkv, qbuf, kbuf, vbuf);
  hipLaunchKernelGGL(k_attn,      dim3(4096*3), dim3(64), 0, stream,
                     (const uint32_t*)qbuf, (const uint32_t*)kbuf, (const uint32_t*)vbuf,
                     offscl, rpb, (float*)d_out);
  hipLaunchKernelGGL(k_proj_mfma, dim3(16*196), dim3(256), 0, stream,
                     (const float*)d_out, w_proj, b_proj, (float*)d_out);
}

// Round 5
// 225.770 us; speedup vs baseline: 3.3546x; 1.1389x over previous
//
#include <hip/hip_runtime.h>
#include <hip/hip_bf16.h>
#include <stdint.h>

#define NB 16
#define CDIM 96
#define HW 112
#define NPOS (HW*HW)      // 12544
#define NHEAD 3
#define DH 32
#define WN 16
#define NWIN (WN*WN)
#define SCALE 0.17677669529663687f

typedef __attribute__((ext_vector_type(8))) short bf16x8;
typedef __attribute__((ext_vector_type(4))) float f32x4;

// ---------- bf16 helpers ----------
__device__ __forceinline__ float bfbits_lo(uint32_t w){ union{uint32_t u; float f;} a; a.u = w<<16; return a.f; }
__device__ __forceinline__ float bfbits_hi(uint32_t w){ union{uint32_t u; float f;} a; a.u = w & 0xFFFF0000u; return a.f; }
__device__ __forceinline__ uint32_t packbf(float x, float y){
  union{float f; uint32_t u;} a, b; a.f = x; b.f = y;
  uint32_t ua = a.u + 0x7FFFu + ((a.u>>16)&1u);
  uint32_t ub = b.u + 0x7FFFu + ((b.u>>16)&1u);
  return (ua>>16) | (ub & 0xFFFF0000u);
}
__device__ __forceinline__ unsigned short f2bf(float x){
  union{float f; uint32_t u;} a; a.f = x;
  return (unsigned short)((a.u + 0x7FFFu + ((a.u>>16)&1u))>>16);
}

// ---------- K1: 7x7 mean pool + leaky relu ----------
__global__ void k_pool_act(const float* __restrict__ x, float* __restrict__ act){
  int n = blockIdx.x*256 + threadIdx.x;
  int ww = n & 15; int wh = (n>>4)&15; int bc = n>>8;
  const float* src = x + (size_t)bc*NPOS + (size_t)(wh*7)*HW + ww*7;
  float s = 0.f;
  #pragma unroll
  for (int r=0;r<7;r++){
    const float* row = src + r*HW;
    s += row[0]+row[1]+row[2]+row[3]+row[4]+row[5]+row[6];
  }
  s *= (1.f/49.f);
  act[n] = s > 0.f ? s : 0.01f*s;
}

// ---------- K2: offsets / scales per window ----------
__global__ void k_offscl(const float* __restrict__ act,
                         const float* __restrict__ woff, const float* __restrict__ boff,
                         const float* __restrict__ wscl, const float* __restrict__ bscl,
                         float4* __restrict__ offscl){
  int n = blockIdx.x*256 + threadIdx.x;
  int b = n >> 8; int wpos = n & 255;
  float accO[6], accS[6];
  #pragma unroll
  for (int o=0;o<6;o++){ accO[o]=boff[o]; accS[o]=bscl[o]; }
  const float* a = act + (size_t)b*CDIM*NWIN + wpos;
  for (int c=0;c<CDIM;c++){
    float av = a[(size_t)c*NWIN];
    #pragma unroll
    for (int o=0;o<6;o++){ accO[o] += av*woff[o*CDIM+c]; accS[o] += av*wscl[o*CDIM+c]; }
  }
  #pragma unroll
  for (int h=0;h<NHEAD;h++){
    float4 r;
    r.x = accO[2*h]   * (1.f/16.f);
    r.y = accO[2*h+1] * (1.f/16.f);
    r.z = accS[2*h];
    r.w = accS[2*h+1];
    offscl[(size_t)(b*NHEAD+h)*NWIN + wpos] = r;
  }
}

// ---------- K2b: padded bias table [3][64 q][64 k]; k>=49 -> -1e30 ----------
__global__ void k_bias_pre(const float* __restrict__ rpb, float* __restrict__ bias_g){
  int n = blockIdx.x*256 + threadIdx.x;
  if (n >= 3*64*64) return;
  int h = n >> 12; int q = (n>>6)&63; int k = n&63;
  float v = -1e30f;
  if (k < 49){
    int qc = q < 49 ? q : 48;
    int qi = qc/7, qj = qc - (qc/7)*7;
    int ki = k/7,  kj = k - (k/7)*7;
    v = rpb[((qi-ki+6)*13 + (qj-kj+6))*3 + h];
  }
  bias_g[n] = v;
}

// ---------- K3: qkv projection via bf16 MFMA (scale folded into q) ----------
__launch_bounds__(256)
__global__ void k_qkv_mfma(const float* __restrict__ x, const float* __restrict__ wqkv,
                           const float* __restrict__ bqkv,
                           unsigned short* __restrict__ q, unsigned short* __restrict__ kk,
                           unsigned short* __restrict__ v){
  __shared__ float xf[96*72];
  __shared__ uint4 xbf4[64*13];
  __shared__ uint4 wbf4[96*13];
  const int t = threadIdx.x;
  const int b = blockIdx.x / 196;
  const int p0 = (blockIdx.x % 196) * 64;

  #pragma unroll
  for (int i=0;i<6;i++){
    int f = t + i*256; int c = f>>4; int p4 = (f&15)*4;
    *(float4*)(xf + c*72 + p4) = *(const float4*)(x + (size_t)(b*CDIM+c)*NPOS + p0 + p4);
  }
  __syncthreads();
  #pragma unroll
  for (int i=0;i<3;i++){
    int u = t + i*256; int pos = u & 63; int oct = u >> 6;
    uint32_t pk0 = packbf(xf[(oct*8+0)*72+pos], xf[(oct*8+1)*72+pos]);
    uint32_t pk1 = packbf(xf[(oct*8+2)*72+pos], xf[(oct*8+3)*72+pos]);
    uint32_t pk2 = packbf(xf[(oct*8+4)*72+pos], xf[(oct*8+5)*72+pos]);
    uint32_t pk3 = packbf(xf[(oct*8+6)*72+pos], xf[(oct*8+7)*72+pos]);
    xbf4[pos*13 + oct] = make_uint4(pk0,pk1,pk2,pk3);
  }

  const int lane = t & 63, wv = t >> 6;
  const int g = lane >> 4, r16 = lane & 15;

  for (int s=0;s<3;s++){
    if (s) __syncthreads();
    #pragma unroll
    for (int i=0;i<9;i++){
      int f = t + i*256; int o = f/24; int c4m = f%24;
      float4 wvv = *(const float4*)(wqkv + (size_t)(s*96+o)*CDIM + c4m*4);
      ((uint2*)wbf4)[o*26 + c4m] = make_uint2(packbf(wvv.x,wvv.y), packbf(wvv.z,wvv.w));
    }
    __syncthreads();

    f32x4 acc[6];
    #pragma unroll
    for (int nf=0;nf<6;nf++) acc[nf] = (f32x4){0.f,0.f,0.f,0.f};
    #pragma unroll
    for (int ks=0;ks<3;ks++){
      bf16x8 a = *(const bf16x8*)&xbf4[(wv*16 + r16)*13 + ks*4 + g];
      #pragma unroll
      for (int nf=0;nf<6;nf++){
        bf16x8 bb = *(const bf16x8*)&wbf4[(nf*16 + r16)*13 + ks*4 + g];
        acc[nf] = __builtin_amdgcn_mfma_f32_16x16x32_bf16(a, bb, acc[nf], 0,0,0);
      }
    }
    unsigned short* dst = (s==0)?q:((s==1)?kk:v);
    float sc = (s==0) ? SCALE : 1.f;
    #pragma unroll
    for (int nf=0;nf<6;nf++){
      int o = nf*16 + r16; int h = o>>5; int d = o&31;
      float bv = bqkv[s*96+o];
      size_t base = ((size_t)(b*NHEAD+h)*NPOS + p0 + wv*16 + g*4)*DH + d;
      #pragma unroll
      for (int rr=0;rr<4;rr++)
        dst[base + (size_t)rr*DH] = f2bf((acc[nf][rr] + bv)*sc);
    }
  }
}

// ---------- K4: fused bilinear sample + window attention (MFMA) ----------
__device__ __forceinline__ void load_row_fma(const uint32_t* __restrict__ src, float w, float* acc){
  const uint4* p4 = (const uint4*)src;
  #pragma unroll
  for (int r=0;r<4;r++){
    uint4 u = p4[r];
    acc[r*8+0] += w*bfbits_lo(u.x); acc[r*8+1] += w*bfbits_hi(u.x);
    acc[r*8+2] += w*bfbits_lo(u.y); acc[r*8+3] += w*bfbits_hi(u.y);
    acc[r*8+4] += w*bfbits_lo(u.z); acc[r*8+5] += w*bfbits_hi(u.z);
    acc[r*8+6] += w*bfbits_lo(u.w); acc[r*8+7] += w*bfbits_hi(u.w);
  }
}

// Block = 128 threads = 2 independent waves; wave = one window-head.
// Per-wave LDS 16KB: K[64][32] bf16 (swz), V^T[32][64] bf16 (swz), P[64][64] bf16 (swz).
// Swizzle: 16B slot index XOR'd with (row & (nslots-1)).
__launch_bounds__(128)
__global__ void k_attn_mfma(const unsigned short* __restrict__ qb,
                            const unsigned short* __restrict__ kb,
                            const unsigned short* __restrict__ vb,
                            const float4* __restrict__ offscl,
                            const float* __restrict__ bias_g,
                            float* __restrict__ aout){
  __shared__ unsigned short lds_u[2*8192];   // 32 KB
  const int h   = blockIdx.x % 3;
  const int grp = blockIdx.x / 3;            // 0..2047
  const int wv  = threadIdx.x >> 6;
  const int lane = threadIdx.x & 63;
  const int win = grp*2 + wv;                // 0..4095
  const int b = win>>8, wh=(win>>4)&15, ww=win&15;
  const int bh = b*NHEAD + h;
  const int g = lane>>4, r16 = lane&15;

  unsigned short* K_s  = lds_u + wv*8192;          // [64][32]
  unsigned short* VT_s = lds_u + wv*8192 + 2048;   // [32][64]
  unsigned short* P_s  = lds_u + wv*8192 + 4096;   // [64][64]

  // ---- Q fragments straight from global (B operand: col=q, k=dh) ----
  uint4 qf[4];
  #pragma unroll
  for (int qt=0;qt<4;qt++){
    int qq = qt*16 + r16; if (qq > 48) qq = 48;
    int qi = qq/7; int qj = qq - qi*7;    // NOTE: plain div — hand magic (n*585)>>12 is WRONG at n=7m
    size_t pos = (size_t)(wh*7+qi)*HW + ww*7 + qj;
    qf[qt] = *(const uint4*)(qb + ((size_t)bh*NPOS + pos)*DH + g*8);
  }

  // ---- bilinear sampling: lane = kv position ----
  float krow[32], vrow[32];
  #pragma unroll
  for (int d=0;d<32;d++){ krow[d]=0.f; vrow[d]=0.f; }
  if (lane < 49){
    float4 os = offscl[(size_t)bh*NWIN + (wh*16+ww)];
    int ki = lane/7; int kj = lane - ki*7;
    float px = (float)(ww*7+kj) + (float)(kj-3)*os.z + 55.5f*os.x;
    float py = (float)(wh*7+ki) + (float)(ki-3)*os.w + 55.5f*os.y;
    float x0f = floorf(px), y0f = floorf(py);
    float fx = px-x0f, fy = py-y0f;
    int x0 = (int)x0f, y0 = (int)y0f;
    float wts[4] = {(1.f-fx)*(1.f-fy), fx*(1.f-fy), (1.f-fx)*fy, fx*fy};
    #pragma unroll
    for (int nb=0; nb<4; nb++){
      int xi = x0 + (nb&1);
      int yi = y0 + ((nb>>1)&1);
      if (xi>=0 && xi<HW && yi>=0 && yi<HW){
        size_t base = ((size_t)bh*NPOS + (size_t)yi*HW + xi)*DH;
        load_row_fma((const uint32_t*)(kb + base), wts[nb], krow);
        load_row_fma((const uint32_t*)(vb + base), wts[nb], vrow);
      }
    }
  }
  // K rows [kpos][32] bf16, 4 slots of 16B, slot ^= (row&3)
  #pragma unroll
  for (int c16=0;c16<4;c16++){
    uint4 pk = make_uint4(packbf(krow[c16*8+0],krow[c16*8+1]), packbf(krow[c16*8+2],krow[c16*8+3]),
                          packbf(krow[c16*8+4],krow[c16*8+5]), packbf(krow[c16*8+6],krow[c16*8+7]));
    *(uint4*)&K_s[lane*32 + ((c16 ^ (lane&3))*8)] = pk;
  }
  // V^T [dh][kpos] bf16, 8 slots of 16B per row, slot ^= (dh&7); column write = b16 each
  #pragma unroll
  for (int d=0;d<32;d++){
    VT_s[d*64 + (((lane>>3) ^ (d&7))*8) + (lane&7)] = f2bf(vrow[d]);
  }

  // ---- S^T = K * Q^T + bias (C-init from global bias table) ----
  const float* bias_h = bias_g + h*4096;
  f32x4 acc[4][4];                           // [at = kpos tile][qt]
  #pragma unroll
  for (int qt=0;qt<4;qt++){
    int qq = qt*16 + r16;
    #pragma unroll
    for (int at=0;at<4;at++)
      acc[at][qt] = *(const f32x4*)(bias_h + qq*64 + at*16 + g*4);
  }
  #pragma unroll
  for (int at=0;at<4;at++){
    bf16x8 a = *(const bf16x8*)&K_s[(at*16+r16)*32 + ((g ^ (r16&3))*8)];
    #pragma unroll
    for (int qt=0;qt<4;qt++)
      acc[at][qt] = __builtin_amdgcn_mfma_f32_16x16x32_bf16(a, *(const bf16x8*)&qf[qt], acc[at][qt], 0,0,0);
  }

  // ---- softmax over k (rows of S^T): in-lane 16 values + shfl over lane>>4 ----
  #pragma unroll
  for (int qt=0;qt<4;qt++){
    float m = acc[0][qt][0];
    #pragma unroll
    for (int at=0;at<4;at++)
      #pragma unroll
      for (int rr=0;rr<4;rr++) m = fmaxf(m, acc[at][qt][rr]);
    m = fmaxf(m, __shfl_xor(m, 16));
    m = fmaxf(m, __shfl_xor(m, 32));
    float s = 0.f;
    #pragma unroll
    for (int at=0;at<4;at++)
      #pragma unroll
      for (int rr=0;rr<4;rr++){ float e = __expf(acc[at][qt][rr]-m); acc[at][qt][rr]=e; s+=e; }
    s += __shfl_xor(s, 16);
    s += __shfl_xor(s, 32);
    float rl = 1.f/s;
    #pragma unroll
    for (int at=0;at<4;at++)
      #pragma unroll
      for (int rr=0;rr<4;rr++) acc[at][qt][rr] *= rl;
  }

  // ---- P -> LDS [q][k] bf16 (8 slots/row, slot ^= (q&7)) ----
  #pragma unroll
  for (int qt=0;qt<4;qt++){
    int qq = qt*16 + r16;
    #pragma unroll
    for (int at=0;at<4;at++){
      uint2 pk = make_uint2(packbf(acc[at][qt][0], acc[at][qt][1]),
                            packbf(acc[at][qt][2], acc[at][qt][3]));
      *(uint2*)&P_s[qq*64 + (((2*at + (g>>1)) ^ (qq&7))*8) + 4*(g&1)] = pk;
    }
  }

  // ---- O = P x V : A = P rows, B = V^T rows ----
  f32x4 o[4][2];
  #pragma unroll
  for (int mt=0;mt<4;mt++){ o[mt][0]=(f32x4){0,0,0,0}; o[mt][1]=(f32x4){0,0,0,0}; }
  #pragma unroll
  for (int kt=0;kt<2;kt++){
    bf16x8 bfr[2];
    #pragma unroll
    for (int nt=0;nt<2;nt++){
      int dh = nt*16 + r16;
      bfr[nt] = *(const bf16x8*)&VT_s[dh*64 + (((4*kt+g) ^ (r16&7))*8)];
    }
    #pragma unroll
    for (int mt=0;mt<4;mt++){
      int qq = mt*16 + r16;
      bf16x8 a = *(const bf16x8*)&P_s[qq*64 + (((4*kt+g) ^ (r16&7))*8)];
      o[mt][0] = __builtin_amdgcn_mfma_f32_16x16x32_bf16(a, bfr[0], o[mt][0], 0,0,0);
      o[mt][1] = __builtin_amdgcn_mfma_f32_16x16x32_bf16(a, bfr[1], o[mt][1], 0,0,0);
    }
  }

  // ---- store (channel-major f32), skip q-pad rows ----
  float* outbase = aout + ((size_t)b*CDIM + h*DH)*NPOS;
  #pragma unroll
  for (int mt=0;mt<4;mt++){
    #pragma unroll
    for (int rr=0;rr<4;rr++){
      int qq = mt*16 + 4*g + rr;
      if (qq < 49){
        int qi = qq/7; int qj = qq - qi*7;
        size_t sp = (size_t)(wh*7+qi)*HW + ww*7 + qj;
        outbase[(size_t)r16*NPOS + sp]      = o[mt][0][rr];
        outbase[(size_t)(16+r16)*NPOS + sp] = o[mt][1][rr];
      }
    }
  }
}

// ---------- K5: output projection via bf16 MFMA, IN PLACE on d_out ----------
__launch_bounds__(256)
__global__ void k_proj_mfma(const float* yin, const float* __restrict__ wproj,
                            const float* __restrict__ bproj, float* yout){
  __shared__ float xf[96*72];
  __shared__ uint4 xbf4[64*13];
  __shared__ uint4 wbf4[96*13];
  const int t = threadIdx.x;
  const int b = blockIdx.x / 196;
  const int p0 = (blockIdx.x % 196) * 64;

  #pragma unroll
  for (int i=0;i<6;i++){
    int f = t + i*256; int c = f>>4; int p4 = (f&15)*4;
    *(float4*)(xf + c*72 + p4) = *(const float4*)(yin + (size_t)(b*CDIM+c)*NPOS + p0 + p4);
  }
  __syncthreads();
  #pragma unroll
  for (int i=0;i<3;i++){
    int u = t + i*256; int pos = u & 63; int oct = u >> 6;
    uint32_t pk0 = packbf(xf[(oct*8+0)*72+pos], xf[(oct*8+1)*72+pos]);
    uint32_t pk1 = packbf(xf[(oct*8+2)*72+pos], xf[(oct*8+3)*72+pos]);
    uint32_t pk2 = packbf(xf[(oct*8+4)*72+pos], xf[(oct*8+5)*72+pos]);
    uint32_t pk3 = packbf(xf[(oct*8+6)*72+pos], xf[(oct*8+7)*72+pos]);
    xbf4[pos*13 + oct] = make_uint4(pk0,pk1,pk2,pk3);
  }
  #pragma unroll
  for (int i=0;i<9;i++){
    int f = t + i*256; int o = f/24; int c4m = f%24;
    float4 wvv = *(const float4*)(wproj + (size_t)o*CDIM + c4m*4);
    ((uint2*)wbf4)[o*26 + c4m] = make_uint2(packbf(wvv.x,wvv.y), packbf(wvv.z,wvv.w));
  }
  __syncthreads();

  const int lane = t & 63, wv = t >> 6;
  const int g = lane >> 4, r16 = lane & 15;
  f32x4 acc[6];
  #pragma unroll
  for (int nf=0;nf<6;nf++) acc[nf] = (f32x4){0.f,0.f,0.f,0.f};
  #pragma unroll
  for (int ks=0;ks<3;ks++){
    bf16x8 a = *(const bf16x8*)&xbf4[(wv*16 + r16)*13 + ks*4 + g];
    #pragma unroll
    for (int nf=0;nf<6;nf++){
      bf16x8 bb = *(const bf16x8*)&wbf4[(nf*16 + r16)*13 + ks*4 + g];
      acc[nf] = __builtin_amdgcn_mfma_f32_16x16x32_bf16(a, bb, acc[nf], 0,0,0);
    }
  }
  #pragma unroll
  for (int nf=0;nf<6;nf++){
    int o = nf*16 + r16;
    float bv = bproj[o];
    float* dst = yout + (size_t)(b*CDIM+o)*NPOS + p0 + wv*16 + g*4;
    #pragma unroll
    for (int rr=0;rr<4;rr++) dst[rr] = acc[nf][rr] + bv;
  }
}

extern "C" void kernel_launch(void* const* d_in, const int* in_sizes, int n_in,
                              void* d_out, int out_size, void* d_ws, size_t ws_size,
                              hipStream_t stream) {
  const float* x      = (const float*)d_in[0];
  const float* w_qkv  = (const float*)d_in[1];
  const float* b_qkv  = (const float*)d_in[2];
  const float* w_off  = (const float*)d_in[3];
  const float* b_off  = (const float*)d_in[4];
  const float* w_scl  = (const float*)d_in[5];
  const float* b_scl  = (const float*)d_in[6];
  const float* rpb    = (const float*)d_in[7];
  const float* w_proj = (const float*)d_in[8];
  const float* b_proj = (const float*)d_in[9];

  char* ws = (char*)d_ws;
  float*   act    = (float*)(ws + 0);                  // 1,572,864 B
  float4*  offscl = (float4*)(ws + 1572864);           //   196,608 B
  float*   bias_g = (float*)(ws + 1769472);            //    49,152 B
  const size_t QKV_BYTES = (size_t)NB*NHEAD*NPOS*DH*2; // 38,535,168 B each
  unsigned short* qbuf = (unsigned short*)(ws + 2097152);
  unsigned short* kbuf = (unsigned short*)(ws + 2097152 + QKV_BYTES);
  unsigned short* vbuf = (unsigned short*)(ws + 2097152 + 2*QKV_BYTES);

  hipLaunchKernelGGL(k_pool_act,  dim3(1536), dim3(256), 0, stream, x, act);
  hipLaunchKernelGGL(k_offscl,    dim3(16),   dim3(256), 0, stream, act, w_off, b_off, w_scl, b_scl, offscl);
  hipLaunchKernelGGL(k_bias_pre,  dim3(48),   dim3(256), 0, stream, rpb, bias_g);
  hipLaunchKernelGGL(k_qkv_mfma,  dim3(16*196), dim3(256), 0, stream, x, w_qkv, b_qkv, qbuf, kbuf, vbuf);
  hipLaunchKernelGGL(k_attn_mfma, dim3(3*2048), dim3(128), 0, stream,
                     qbuf, kbuf, vbuf, offscl, bias_g, (float*)d_out);
  hipLaunchKernelGGL(k_proj_mfma, dim3(16*196), dim3(256), 0, stream,
                     (const float*)d_out, w_proj, b_proj, (float*)d_out);
}